// Round 6
// baseline (365.135 us; speedup 1.0000x reference)
//
#include <hip/hip_runtime.h>

#define B_ 64
#define N_ 4096
#define C_ 10
#define D_ 8
#define E_ 16
#define EPS_ 1e-7f
#define NT_ 8
#define NBLK_ (N_ / NT_)       // 512 blocks
#define KREP_ 8                // atomic replicas (one per XCD)
#define SVE_ (B_ * C_ * E_)    // 10240 floats

__device__ inline float reduce16(float v) {
    v += __shfl_xor(v, 1);
    v += __shfl_xor(v, 2);
    v += __shfl_xor(v, 4);
    v += __shfl_xor(v, 8);
    return v;
}

// bf16 pack (truncation) for register-resident v_cum
__device__ inline unsigned pack2(float a, float b) {
    return (__float_as_uint(a) >> 16) | (__float_as_uint(b) & 0xffff0000u);
}
__device__ inline float lo2(unsigned u) { return __uint_as_float(u << 16); }
__device__ inline float hi2(unsigned u) { return __uint_as_float(u & 0xffff0000u); }

// Block: 256 thr = 4 waves = (h: b-half) x (np2: n-quad). Thread owns TWO b
// (b0 = h*32+bl, b1 = b0+16) so each W ds_read_b128 feeds 8 FMAs.
// Lane: eq = lane&3 (e-quad), bl = lane>>2.
// Output: block-combined sums atomicAdd'ed into s_raw[slot&7][b][c][e].
template <bool UNIFORM>
__global__ __launch_bounds__(256, 2) void caps_pass(
    const float* __restrict__ x, const float* __restrict__ W,
    const float* __restrict__ v_cum, float* __restrict__ s_raw)
{
    __shared__ float4 lds4[2624];   // 41984B: W tile (2560 f4) / combine scratch overlay

    const int tid  = (int)threadIdx.x;
    const int slot = (int)blockIdx.x;
    const int n0   = slot * NT_;

    {   // stage W[n0..n0+8) -> LDS (40 KB, coalesced float4)
        const float4* gsrc = (const float4*)(W + (size_t)n0 * (C_ * D_ * E_));
#pragma unroll
        for (int it = 0; it < 10; ++it)
            lds4[it * 256 + tid] = gsrc[it * 256 + tid];
    }
    __syncthreads();

    const int w    = tid >> 6;
    const int lane = tid & 63;
    const int eq   = lane & 3;
    const int bl   = lane >> 2;
    const int h    = w & 1;
    const int np2  = w >> 1;
    const int b0   = h * 32 + bl;
    const int b1   = b0 + 16;

    unsigned vcp0[C_][2], vcp1[C_][2];
    if (!UNIFORM) {
#pragma unroll
        for (int c = 0; c < C_; ++c) {
            const float4 a = *(const float4*)(v_cum + (b0 * C_ + c) * E_ + eq * 4);
            vcp0[c][0] = pack2(a.x, a.y); vcp0[c][1] = pack2(a.z, a.w);
            const float4 d = *(const float4*)(v_cum + (b1 * C_ + c) * E_ + eq * 4);
            vcp1[c][0] = pack2(d.x, d.y); vcp1[c][1] = pack2(d.z, d.w);
        }
    }

    float4 acc0[C_], acc1[C_];
#pragma unroll
    for (int c = 0; c < C_; ++c) {
        acc0[c] = make_float4(0.f, 0.f, 0.f, 0.f);
        acc1[c] = make_float4(0.f, 0.f, 0.f, 0.f);
    }

#pragma unroll
    for (int j = 0; j < NT_ / 2; ++j) {
        const int nl = np2 * (NT_ / 2) + j;
        const int n  = n0 + nl;

        float xv0[D_], xv1[D_];
        {
            const float4* xp = (const float4*)(x + ((size_t)b0 * N_ + n) * D_);
            const float4 a = xp[0], d = xp[1];
            xv0[0]=a.x; xv0[1]=a.y; xv0[2]=a.z; xv0[3]=a.w;
            xv0[4]=d.x; xv0[5]=d.y; xv0[6]=d.z; xv0[7]=d.w;
        }
        {
            const float4* xp = (const float4*)(x + ((size_t)b1 * N_ + n) * D_);
            const float4 a = xp[0], d = xp[1];
            xv1[0]=a.x; xv1[1]=a.y; xv1[2]=a.z; xv1[3]=a.w;
            xv1[4]=d.x; xv1[5]=d.y; xv1[6]=d.z; xv1[7]=d.w;
        }

        const float4* wl = (const float4*)lds4 + nl * 320 + eq;

        float4 uh0[C_], uh1[C_];
#pragma unroll
        for (int c = 0; c < C_; ++c) {
            float4 u0 = make_float4(0.f, 0.f, 0.f, 0.f);
            float4 u1 = make_float4(0.f, 0.f, 0.f, 0.f);
#pragma unroll
            for (int d = 0; d < D_; ++d) {
                const float4 wq = wl[(c * D_ + d) * 4];
                u0.x = fmaf(xv0[d], wq.x, u0.x);
                u0.y = fmaf(xv0[d], wq.y, u0.y);
                u0.z = fmaf(xv0[d], wq.z, u0.z);
                u0.w = fmaf(xv0[d], wq.w, u0.w);
                u1.x = fmaf(xv1[d], wq.x, u1.x);
                u1.y = fmaf(xv1[d], wq.y, u1.y);
                u1.z = fmaf(xv1[d], wq.z, u1.z);
                u1.w = fmaf(xv1[d], wq.w, u1.w);
            }
            uh0[c] = u0; uh1[c] = u1;
        }

        float wgt0[C_], wgt1[C_];
        if (UNIFORM) {
#pragma unroll
            for (int c = 0; c < C_; ++c) { wgt0[c] = 0.1f; wgt1[c] = 0.1f; }
        } else {
#pragma unroll
            for (int c = 0; c < C_; ++c) {
                float t0 = uh0[c].x * lo2(vcp0[c][0]) + uh0[c].y * hi2(vcp0[c][0])
                         + uh0[c].z * lo2(vcp0[c][1]) + uh0[c].w * hi2(vcp0[c][1]);
                t0 += __shfl_xor(t0, 1); t0 += __shfl_xor(t0, 2);
                wgt0[c] = t0;
                float t1 = uh1[c].x * lo2(vcp1[c][0]) + uh1[c].y * hi2(vcp1[c][0])
                         + uh1[c].z * lo2(vcp1[c][1]) + uh1[c].w * hi2(vcp1[c][1]);
                t1 += __shfl_xor(t1, 1); t1 += __shfl_xor(t1, 2);
                wgt1[c] = t1;
            }
            float m0 = wgt0[0], m1 = wgt1[0];
#pragma unroll
            for (int c = 1; c < C_; ++c) { m0 = fmaxf(m0, wgt0[c]); m1 = fmaxf(m1, wgt1[c]); }
            float s0 = 0.f, s1 = 0.f;
#pragma unroll
            for (int c = 0; c < C_; ++c) {
                wgt0[c] = __expf(wgt0[c] - m0); s0 += wgt0[c];
                wgt1[c] = __expf(wgt1[c] - m1); s1 += wgt1[c];
            }
            const float i0 = 1.f / s0, i1 = 1.f / s1;
#pragma unroll
            for (int c = 0; c < C_; ++c) { wgt0[c] *= i0; wgt1[c] *= i1; }
        }

#pragma unroll
        for (int c = 0; c < C_; ++c) {
            acc0[c].x = fmaf(wgt0[c], uh0[c].x, acc0[c].x);
            acc0[c].y = fmaf(wgt0[c], uh0[c].y, acc0[c].y);
            acc0[c].z = fmaf(wgt0[c], uh0[c].z, acc0[c].z);
            acc0[c].w = fmaf(wgt0[c], uh0[c].w, acc0[c].w);
            acc1[c].x = fmaf(wgt1[c], uh1[c].x, acc1[c].x);
            acc1[c].y = fmaf(wgt1[c], uh1[c].y, acc1[c].y);
            acc1[c].z = fmaf(wgt1[c], uh1[c].z, acc1[c].z);
            acc1[c].w = fmaf(wgt1[c], uh1[c].w, acc1[c].w);
        }
    }

    __syncthreads();   // W tile dead; reuse LDS as combine scratch (stride 41 f4/b)

    if (np2 == 1) {
#pragma unroll
        for (int c = 0; c < C_; ++c) {
            lds4[b0 * 41 + c * 4 + eq] = acc0[c];
            lds4[b1 * 41 + c * 4 + eq] = acc1[c];
        }
    }
    __syncthreads();
    if (np2 == 0) {
        float* sr = s_raw + (size_t)(slot & (KREP_ - 1)) * SVE_;
#pragma unroll
        for (int c = 0; c < C_; ++c) {
            const float4 o0 = lds4[b0 * 41 + c * 4 + eq];
            const float4 o1 = lds4[b1 * 41 + c * 4 + eq];
            float* p0 = sr + (b0 * C_ + c) * E_ + eq * 4;
            atomicAdd(p0 + 0, acc0[c].x + o0.x);
            atomicAdd(p0 + 1, acc0[c].y + o0.y);
            atomicAdd(p0 + 2, acc0[c].z + o0.z);
            atomicAdd(p0 + 3, acc0[c].w + o0.w);
            float* p1 = sr + (b1 * C_ + c) * E_ + eq * 4;
            atomicAdd(p1 + 0, acc1[c].x + o1.x);
            atomicAdd(p1 + 1, acc1[c].y + o1.y);
            atomicAdd(p1 + 2, acc1[c].z + o1.z);
            atomicAdd(p1 + 3, acc1[c].w + o1.w);
        }
    }
}

// 64 blocks (one per b): sum 8 replicas, re-zero them, squash, update v_cum/out.
// mode: 0 = v_cum = v, 1 = v_cum += v, 2 = out = v
__global__ __launch_bounds__(256) void caps_reduce(
    float* __restrict__ s_raw, float* __restrict__ v_cum,
    float* __restrict__ out, int mode)
{
    const int b = (int)blockIdx.x;
    const int tid = (int)threadIdx.x;
    if (tid >= C_ * E_) return;
    float s = 0.f;
#pragma unroll
    for (int r = 0; r < KREP_; ++r) {
        float* p = s_raw + (size_t)r * SVE_ + b * (C_ * E_) + tid;
        s += *p;
        *p = 0.f;   // clean for next pass / next graph replay
    }
    const float s2 = reduce16(s * s);
    const float scale = (s2 / (1.f + s2)) * rsqrtf(s2 + EPS_);
    const float v = scale * s;
    if (mode == 2)      out[b * (C_ * E_) + tid] = v;
    else if (mode == 0) v_cum[b * (C_ * E_) + tid] = v;
    else                v_cum[b * (C_ * E_) + tid] += v;
}

extern "C" void kernel_launch(void* const* d_in, const int* in_sizes, int n_in,
                              void* d_out, int out_size, void* d_ws, size_t ws_size,
                              hipStream_t stream) {
    const float* x = (const float*)d_in[0];
    const float* W = (const float*)d_in[1];
    float* out = (float*)d_out;

    float* s_raw = (float*)d_ws;                               // 8*10240*4 = 320 KB
    float* v_cum = (float*)((char*)d_ws + (size_t)KREP_ * SVE_ * sizeof(float));

    hipMemsetAsync(s_raw, 0, (size_t)KREP_ * SVE_ * sizeof(float), stream);

    for (int t = 0; t < 3; ++t) {
        if (t == 0)
            caps_pass<true ><<<dim3(NBLK_), 256, 0, stream>>>(x, W, v_cum, s_raw);
        else
            caps_pass<false><<<dim3(NBLK_), 256, 0, stream>>>(x, W, v_cum, s_raw);
        caps_reduce<<<dim3(B_), 256, 0, stream>>>(s_raw, v_cum, out, t);
    }
}

// Round 7
// 344.490 us; speedup vs baseline: 1.0599x; 1.0599x over previous
//
#include <hip/hip_runtime.h>

#define B_ 64
#define N_ 4096
#define C_ 10
#define D_ 8
#define E_ 16
#define EPS_ 1e-7f
#define NT_ 16
#define NSLOT_ (N_ / NT_)        // 256 blocks / partial slots
#define ROW4_ 41                 // stile row stride in float4 (164 dwords: pad)

__device__ inline float reduce16(float v) {
    v += __shfl_xor(v, 1);
    v += __shfl_xor(v, 2);
    v += __shfl_xor(v, 4);
    v += __shfl_xor(v, 8);
    return v;
}

__device__ inline unsigned pack2(float a, float b) {
    return (__float_as_uint(a) >> 16) | (__float_as_uint(b) & 0xffff0000u);
}
__device__ inline float lo2(unsigned u) { return __uint_as_float(u << 16); }
__device__ inline float hi2(unsigned u) { return __uint_as_float(u & 0xffff0000u); }

// Block: 512 thr = 8 waves = (h: b-half) x (np4: n-group). Thread owns TWO b
// (b0 = h*32+bl, b1 = b0+16): each W ds_read_b128 (broadcast, conflict-free)
// feeds 8 FMAs. NT=16 n per block, W tile re-staged 2x8n in 40KB LDS.
// Block-level combine in padded stile, then ONE coalesced partial write
// per block -> partial[b][slot][ce] (10 MB total, L2/L3-resident).
template <bool UNIFORM>
__global__ __launch_bounds__(512, 2) void caps_pass(
    const float* __restrict__ x, const float* __restrict__ W,
    const float* __restrict__ v_cum, float* __restrict__ partial)
{
    __shared__ float4 wtile[2560];          // 40960 B (8 n x 1280 f)
    __shared__ float4 stile[B_ * ROW4_];    // 41984 B combine scratch

    const int tid  = (int)threadIdx.x;
    const int slot = (int)blockIdx.x;

    const int w    = tid >> 6;
    const int lane = tid & 63;
    const int eq   = lane & 3;
    const int bl   = lane >> 2;
    const int h    = w & 1;
    const int np4  = w >> 1;
    const int b0   = h * 32 + bl;
    const int b1   = b0 + 16;

    unsigned vcp0[C_][2], vcp1[C_][2];
    if (!UNIFORM) {
#pragma unroll
        for (int c = 0; c < C_; ++c) {
            const float4 a = *(const float4*)(v_cum + (b0 * C_ + c) * E_ + eq * 4);
            vcp0[c][0] = pack2(a.x, a.y); vcp0[c][1] = pack2(a.z, a.w);
            const float4 d = *(const float4*)(v_cum + (b1 * C_ + c) * E_ + eq * 4);
            vcp1[c][0] = pack2(d.x, d.y); vcp1[c][1] = pack2(d.z, d.w);
        }
    }

    float4 acc0[C_], acc1[C_];
#pragma unroll
    for (int c = 0; c < C_; ++c) {
        acc0[c] = make_float4(0.f, 0.f, 0.f, 0.f);
        acc1[c] = make_float4(0.f, 0.f, 0.f, 0.f);
    }

#pragma unroll
    for (int stage = 0; stage < 2; ++stage) {
        // ---- stage 8 n of W -> LDS (coalesced float4, 5 per thread) ----
        if (stage) __syncthreads();          // prev-stage reads done
        {
            const float4* gsrc = (const float4*)
                (W + ((size_t)slot * NT_ + stage * 8) * (C_ * D_ * E_));
#pragma unroll
            for (int it = 0; it < 5; ++it)
                wtile[it * 512 + tid] = gsrc[it * 512 + tid];
        }
        __syncthreads();

#pragma unroll
        for (int j = 0; j < 2; ++j) {
            const int nl = np4 * 2 + j;
            const int n  = slot * NT_ + stage * 8 + nl;

            float xv0[D_], xv1[D_];
            {
                const float4* xp = (const float4*)(x + ((size_t)b0 * N_ + n) * D_);
                const float4 a = xp[0], d = xp[1];
                xv0[0]=a.x; xv0[1]=a.y; xv0[2]=a.z; xv0[3]=a.w;
                xv0[4]=d.x; xv0[5]=d.y; xv0[6]=d.z; xv0[7]=d.w;
            }
            {
                const float4* xp = (const float4*)(x + ((size_t)b1 * N_ + n) * D_);
                const float4 a = xp[0], d = xp[1];
                xv1[0]=a.x; xv1[1]=a.y; xv1[2]=a.z; xv1[3]=a.w;
                xv1[4]=d.x; xv1[5]=d.y; xv1[6]=d.z; xv1[7]=d.w;
            }

            const float4* wl = wtile + nl * 320 + eq;

            float4 uh0[C_], uh1[C_];
#pragma unroll
            for (int c = 0; c < C_; ++c) {
                float4 u0 = make_float4(0.f, 0.f, 0.f, 0.f);
                float4 u1 = make_float4(0.f, 0.f, 0.f, 0.f);
#pragma unroll
                for (int d = 0; d < D_; ++d) {
                    const float4 wq = wl[(c * D_ + d) * 4];
                    u0.x = fmaf(xv0[d], wq.x, u0.x);
                    u0.y = fmaf(xv0[d], wq.y, u0.y);
                    u0.z = fmaf(xv0[d], wq.z, u0.z);
                    u0.w = fmaf(xv0[d], wq.w, u0.w);
                    u1.x = fmaf(xv1[d], wq.x, u1.x);
                    u1.y = fmaf(xv1[d], wq.y, u1.y);
                    u1.z = fmaf(xv1[d], wq.z, u1.z);
                    u1.w = fmaf(xv1[d], wq.w, u1.w);
                }
                uh0[c] = u0; uh1[c] = u1;
            }

            float wgt0[C_], wgt1[C_];
            if (UNIFORM) {
#pragma unroll
                for (int c = 0; c < C_; ++c) { wgt0[c] = 0.1f; wgt1[c] = 0.1f; }
            } else {
#pragma unroll
                for (int c = 0; c < C_; ++c) {
                    float t0 = uh0[c].x * lo2(vcp0[c][0]) + uh0[c].y * hi2(vcp0[c][0])
                             + uh0[c].z * lo2(vcp0[c][1]) + uh0[c].w * hi2(vcp0[c][1]);
                    t0 += __shfl_xor(t0, 1); t0 += __shfl_xor(t0, 2);
                    wgt0[c] = t0;
                    float t1 = uh1[c].x * lo2(vcp1[c][0]) + uh1[c].y * hi2(vcp1[c][0])
                             + uh1[c].z * lo2(vcp1[c][1]) + uh1[c].w * hi2(vcp1[c][1]);
                    t1 += __shfl_xor(t1, 1); t1 += __shfl_xor(t1, 2);
                    wgt1[c] = t1;
                }
                float m0 = wgt0[0], m1 = wgt1[0];
#pragma unroll
                for (int c = 1; c < C_; ++c) { m0 = fmaxf(m0, wgt0[c]); m1 = fmaxf(m1, wgt1[c]); }
                float s0 = 0.f, s1 = 0.f;
#pragma unroll
                for (int c = 0; c < C_; ++c) {
                    wgt0[c] = __expf(wgt0[c] - m0); s0 += wgt0[c];
                    wgt1[c] = __expf(wgt1[c] - m1); s1 += wgt1[c];
                }
                const float i0 = 1.f / s0, i1 = 1.f / s1;
#pragma unroll
                for (int c = 0; c < C_; ++c) { wgt0[c] *= i0; wgt1[c] *= i1; }
            }

#pragma unroll
            for (int c = 0; c < C_; ++c) {
                acc0[c].x = fmaf(wgt0[c], uh0[c].x, acc0[c].x);
                acc0[c].y = fmaf(wgt0[c], uh0[c].y, acc0[c].y);
                acc0[c].z = fmaf(wgt0[c], uh0[c].z, acc0[c].z);
                acc0[c].w = fmaf(wgt0[c], uh0[c].w, acc0[c].w);
                acc1[c].x = fmaf(wgt1[c], uh1[c].x, acc1[c].x);
                acc1[c].y = fmaf(wgt1[c], uh1[c].y, acc1[c].y);
                acc1[c].z = fmaf(wgt1[c], uh1[c].z, acc1[c].z);
                acc1[c].w = fmaf(wgt1[c], uh1[c].w, acc1[c].w);
            }
        }
    }

    // ---- combine 4 np4-wave-sets in padded stile (round 0 writes, 1-3 RMW) ----
#pragma unroll
    for (int r = 0; r < 4; ++r) {
        __syncthreads();
        if (np4 == r) {
#pragma unroll
            for (int c = 0; c < C_; ++c) {
                const int i0 = b0 * ROW4_ + c * 4 + eq;
                const int i1 = b1 * ROW4_ + c * 4 + eq;
                if (r == 0) {
                    stile[i0] = acc0[c];
                    stile[i1] = acc1[c];
                } else {
                    float4 t0 = stile[i0], t1 = stile[i1];
                    t0.x += acc0[c].x; t0.y += acc0[c].y;
                    t0.z += acc0[c].z; t0.w += acc0[c].w;
                    t1.x += acc1[c].x; t1.y += acc1[c].y;
                    t1.z += acc1[c].z; t1.w += acc1[c].w;
                    stile[i0] = t0;
                    stile[i1] = t1;
                }
            }
        }
    }
    __syncthreads();

    // ---- coalesced partial write: partial[b][slot][ce] ----
    float4* p4 = (float4*)partial;
#pragma unroll
    for (int it = 0; it < 5; ++it) {
        const int i = it * 512 + tid;      // [0, 2560)
        const int bb = i / 40;
        const int rr = i - bb * 40;
        p4[((size_t)bb * NSLOT_ + slot) * 40 + rr] = stile[bb * ROW4_ + rr];
    }
}

// Block per b: sum partial[b][*][ce] (640B coalesced rows), squash, update.
// mode: 0 = v_cum = v, 1 = v_cum += v, 2 = out = v
__global__ __launch_bounds__(512) void caps_reduce(
    const float* __restrict__ partial, float* __restrict__ v_cum,
    float* __restrict__ out, int mode)
{
    const int b = (int)blockIdx.x;
    const int tid = (int)threadIdx.x;
    const int half = tid >> 8;
    const int ce = tid & 255;
    __shared__ float red[2][C_ * E_];
    if (ce < C_ * E_) {
        const int cnt = NSLOT_ >> 1;
        const float* base = partial +
            ((size_t)b * NSLOT_ + (size_t)half * cnt) * (C_ * E_) + ce;
        float s0 = 0.f, s1 = 0.f, s2 = 0.f, s3 = 0.f;
        for (int k = 0; k < cnt; k += 4) {
            s0 += base[(size_t)(k + 0) * (C_ * E_)];
            s1 += base[(size_t)(k + 1) * (C_ * E_)];
            s2 += base[(size_t)(k + 2) * (C_ * E_)];
            s3 += base[(size_t)(k + 3) * (C_ * E_)];
        }
        red[half][ce] = (s0 + s1) + (s2 + s3);
    }
    __syncthreads();
    if (tid < C_ * E_) {
        float s = red[0][tid] + red[1][tid];
        const float s2 = reduce16(s * s);
        const float scale = (s2 / (1.f + s2)) * rsqrtf(s2 + EPS_);
        const float v = scale * s;
        if (mode == 2)      out[b * (C_ * E_) + tid] = v;
        else if (mode == 0) v_cum[b * (C_ * E_) + tid] = v;
        else                v_cum[b * (C_ * E_) + tid] += v;
    }
}

extern "C" void kernel_launch(void* const* d_in, const int* in_sizes, int n_in,
                              void* d_out, int out_size, void* d_ws, size_t ws_size,
                              hipStream_t stream) {
    const float* x = (const float*)d_in[0];
    const float* W = (const float*)d_in[1];
    float* out = (float*)d_out;

    float* partial = (float*)d_ws;   // 256 * 64 * 160 * 4 = 10.5 MB
    float* v_cum = (float*)((char*)d_ws +
        (size_t)NSLOT_ * B_ * C_ * E_ * sizeof(float));

    for (int t = 0; t < 3; ++t) {
        if (t == 0)
            caps_pass<true ><<<dim3(NSLOT_), 512, 0, stream>>>(x, W, v_cum, partial);
        else
            caps_pass<false><<<dim3(NSLOT_), 512, 0, stream>>>(x, W, v_cum, partial);
        caps_reduce<<<dim3(B_), 512, 0, stream>>>(partial, v_cum, out, t);
    }
}

// Round 8
// 196.337 us; speedup vs baseline: 1.8597x; 1.7546x over previous
//
#include <hip/hip_runtime.h>
#include <hip/hip_fp16.h>

#define B_ 64
#define N_ 4096
#define C_ 10
#define D_ 8
#define E_ 16
#define EPS_ 1e-7f
#define NT_ 8
#define NBLK_ (N_ / NT_)          // 512 pass blocks
#define NSLOT_ (NBLK_ * 2)        // 1024 partial slots (one per np-wave-set)
#define PROW_ 80                  // u32 per partial row (160 halfs)

// bf16 truncation pack/unpack (register-resident uh, v_cum)
__device__ inline unsigned pk2(float a, float b) {
    return (__float_as_uint(a) >> 16) | (__float_as_uint(b) & 0xffff0000u);
}
__device__ inline float plo(unsigned u) { return __uint_as_float(u << 16); }
__device__ inline float phi(unsigned u) { return __uint_as_float(u & 0xffff0000u); }
__device__ inline unsigned hpack(float a, float b) {
    __half2 t = __floats2half2_rn(a, b);
    return *(unsigned*)&t;
}

// Block: 256 thr = 4 waves = (h: b-half) x (np: n-half). Thread owns TWO b
// (b0 = h*32 + bl, b1 = b0 + 16): each W ds_read_b128 broadcast feeds 8 FMAs.
// uh kept PACKED bf16 in regs (register diet vs R7's spill); partials fp16.
template <bool UNIFORM>
__global__ __launch_bounds__(256, 2) void caps_pass(
    const float* __restrict__ x, const float* __restrict__ W,
    const float* __restrict__ v_cum, unsigned* __restrict__ partial)
{
    __shared__ float4 wtile[NT_ * 320];   // 40 KB

    const int tid = (int)threadIdx.x;
    const int blk = (int)blockIdx.x;

    {   // stage W[blk*8 .. +8) -> LDS, coalesced float4
        const float4* g = (const float4*)(W + (size_t)blk * (NT_ * 1280));
#pragma unroll
        for (int i = 0; i < 10; ++i)
            wtile[i * 256 + tid] = g[i * 256 + tid];
    }

    const int wv   = tid >> 6;
    const int lane = tid & 63;
    const int eq   = lane & 3;
    const int bl   = lane >> 2;
    const int h    = wv & 1;
    const int np   = wv >> 1;
    const int b0   = h * 32 + bl;
    const int b1   = b0 + 16;

    unsigned vcp0[C_][2], vcp1[C_][2];
    if (!UNIFORM) {
#pragma unroll
        for (int c = 0; c < C_; ++c) {
            const float4 a = *(const float4*)(v_cum + (b0 * C_ + c) * E_ + eq * 4);
            vcp0[c][0] = pk2(a.x, a.y); vcp0[c][1] = pk2(a.z, a.w);
            const float4 d = *(const float4*)(v_cum + (b1 * C_ + c) * E_ + eq * 4);
            vcp1[c][0] = pk2(d.x, d.y); vcp1[c][1] = pk2(d.z, d.w);
        }
    }

    float4 acc0[C_], acc1[C_];
#pragma unroll
    for (int c = 0; c < C_; ++c) {
        acc0[c] = make_float4(0.f, 0.f, 0.f, 0.f);
        acc1[c] = make_float4(0.f, 0.f, 0.f, 0.f);
    }

    __syncthreads();

#pragma unroll 1
    for (int j = 0; j < NT_ / 2; ++j) {
        const int nl = np * (NT_ / 2) + j;
        const int n  = blk * NT_ + nl;

        float xv0[D_], xv1[D_];
        {
            const float4* xp = (const float4*)(x + ((size_t)b0 * N_ + n) * D_);
            const float4 a = xp[0], d = xp[1];
            xv0[0]=a.x; xv0[1]=a.y; xv0[2]=a.z; xv0[3]=a.w;
            xv0[4]=d.x; xv0[5]=d.y; xv0[6]=d.z; xv0[7]=d.w;
        }
        {
            const float4* xp = (const float4*)(x + ((size_t)b1 * N_ + n) * D_);
            const float4 a = xp[0], d = xp[1];
            xv1[0]=a.x; xv1[1]=a.y; xv1[2]=a.z; xv1[3]=a.w;
            xv1[4]=d.x; xv1[5]=d.y; xv1[6]=d.z; xv1[7]=d.w;
        }

        const float4* wl = wtile + nl * 320 + eq;

        if (UNIFORM) {
#pragma unroll
            for (int c = 0; c < C_; ++c) {
#pragma unroll
                for (int d = 0; d < D_; ++d) {
                    const float4 wq = wl[c * 32 + d * 4];
                    acc0[c].x = fmaf(xv0[d], wq.x, acc0[c].x);
                    acc0[c].y = fmaf(xv0[d], wq.y, acc0[c].y);
                    acc0[c].z = fmaf(xv0[d], wq.z, acc0[c].z);
                    acc0[c].w = fmaf(xv0[d], wq.w, acc0[c].w);
                    acc1[c].x = fmaf(xv1[d], wq.x, acc1[c].x);
                    acc1[c].y = fmaf(xv1[d], wq.y, acc1[c].y);
                    acc1[c].z = fmaf(xv1[d], wq.z, acc1[c].z);
                    acc1[c].w = fmaf(xv1[d], wq.w, acc1[c].w);
                }
            }
        } else {
            unsigned uhp0[C_][2], uhp1[C_][2];
            float wgt0[C_], wgt1[C_];
#pragma unroll
            for (int c = 0; c < C_; ++c) {
                float4 u0 = make_float4(0.f, 0.f, 0.f, 0.f);
                float4 u1 = make_float4(0.f, 0.f, 0.f, 0.f);
#pragma unroll
                for (int d = 0; d < D_; ++d) {
                    const float4 wq = wl[c * 32 + d * 4];
                    u0.x = fmaf(xv0[d], wq.x, u0.x);
                    u0.y = fmaf(xv0[d], wq.y, u0.y);
                    u0.z = fmaf(xv0[d], wq.z, u0.z);
                    u0.w = fmaf(xv0[d], wq.w, u0.w);
                    u1.x = fmaf(xv1[d], wq.x, u1.x);
                    u1.y = fmaf(xv1[d], wq.y, u1.y);
                    u1.z = fmaf(xv1[d], wq.z, u1.z);
                    u1.w = fmaf(xv1[d], wq.w, u1.w);
                }
                float t0 = u0.x * plo(vcp0[c][0]);
                t0 = fmaf(u0.y, phi(vcp0[c][0]), t0);
                t0 = fmaf(u0.z, plo(vcp0[c][1]), t0);
                t0 = fmaf(u0.w, phi(vcp0[c][1]), t0);
                t0 += __shfl_xor(t0, 1); t0 += __shfl_xor(t0, 2);
                wgt0[c] = t0;
                float t1 = u1.x * plo(vcp1[c][0]);
                t1 = fmaf(u1.y, phi(vcp1[c][0]), t1);
                t1 = fmaf(u1.z, plo(vcp1[c][1]), t1);
                t1 = fmaf(u1.w, phi(vcp1[c][1]), t1);
                t1 += __shfl_xor(t1, 1); t1 += __shfl_xor(t1, 2);
                wgt1[c] = t1;
                uhp0[c][0] = pk2(u0.x, u0.y); uhp0[c][1] = pk2(u0.z, u0.w);
                uhp1[c][0] = pk2(u1.x, u1.y); uhp1[c][1] = pk2(u1.z, u1.w);
            }
            // softmax over C, no max-sub (|logit| <~ 15, exp safe in f32)
            float s0 = 0.f, s1 = 0.f;
#pragma unroll
            for (int c = 0; c < C_; ++c) {
                wgt0[c] = __expf(wgt0[c]); s0 += wgt0[c];
                wgt1[c] = __expf(wgt1[c]); s1 += wgt1[c];
            }
            const float i0 = 1.f / s0, i1 = 1.f / s1;
#pragma unroll
            for (int c = 0; c < C_; ++c) {
                const float g0 = wgt0[c] * i0, g1 = wgt1[c] * i1;
                acc0[c].x = fmaf(g0, plo(uhp0[c][0]), acc0[c].x);
                acc0[c].y = fmaf(g0, phi(uhp0[c][0]), acc0[c].y);
                acc0[c].z = fmaf(g0, plo(uhp0[c][1]), acc0[c].z);
                acc0[c].w = fmaf(g0, phi(uhp0[c][1]), acc0[c].w);
                acc1[c].x = fmaf(g1, plo(uhp1[c][0]), acc1[c].x);
                acc1[c].y = fmaf(g1, phi(uhp1[c][0]), acc1[c].y);
                acc1[c].z = fmaf(g1, plo(uhp1[c][1]), acc1[c].z);
                acc1[c].w = fmaf(g1, phi(uhp1[c][1]), acc1[c].w);
            }
        }
    }

    // fp16 partial write: partial[b][slot][c*8+eq*2 (+1)] (uint2 = 4 halfs)
    const float fold = UNIFORM ? 0.1f : 1.f;   // softmax(0) = 1/10 folded out
    const int slot = blk * 2 + np;
#pragma unroll
    for (int c = 0; c < C_; ++c) {
        const uint2 p0 = make_uint2(hpack(acc0[c].x * fold, acc0[c].y * fold),
                                    hpack(acc0[c].z * fold, acc0[c].w * fold));
        *(uint2*)(partial + ((size_t)b0 * NSLOT_ + slot) * PROW_ + c * 8 + eq * 2) = p0;
        const uint2 p1 = make_uint2(hpack(acc1[c].x * fold, acc1[c].y * fold),
                                    hpack(acc1[c].z * fold, acc1[c].w * fold));
        *(uint2*)(partial + ((size_t)b1 * NSLOT_ + slot) * PROW_ + c * 8 + eq * 2) = p1;
    }
}

// Block per b: sum partial[b][*][col] (fp16x2 rows, coalesced), squash, update.
// mode: 0 = v_cum = v, 1 = v_cum += v, 2 = out = v
__global__ __launch_bounds__(192) void caps_reduce(
    const unsigned* __restrict__ partial, float* __restrict__ v_cum,
    float* __restrict__ out, int mode)
{
    const int b = (int)blockIdx.x;
    const int tid = (int)threadIdx.x;
    __shared__ float redlo[2][PROW_], redhi[2][PROW_];
    if (tid < 2 * PROW_) {
        const int col = tid % PROW_;
        const int gh  = tid / PROW_;
        const unsigned* base =
            partial + ((size_t)b * NSLOT_ + (size_t)gh * (NSLOT_ / 2)) * PROW_ + col;
        float a0 = 0.f, a1 = 0.f, c0 = 0.f, c1 = 0.f;
        for (int k = 0; k < NSLOT_ / 2; k += 2) {
            const unsigned u0 = base[(size_t)k * PROW_];
            const unsigned u1 = base[(size_t)(k + 1) * PROW_];
            const float2 f0 = __half22float2(*(const __half2*)&u0);
            const float2 f1 = __half22float2(*(const __half2*)&u1);
            a0 += f0.x; c0 += f0.y;
            a1 += f1.x; c1 += f1.y;
        }
        redlo[gh][col] = a0 + a1;
        redhi[gh][col] = c0 + c1;
    }
    __syncthreads();
    if (tid < PROW_) {
        const float slo = redlo[0][tid] + redlo[1][tid];
        const float shi = redhi[0][tid] + redhi[1][tid];
        float p = slo * slo + shi * shi;
        p += __shfl_xor(p, 1); p += __shfl_xor(p, 2); p += __shfl_xor(p, 4);
        const float sc = (p / (1.f + p)) * rsqrtf(p + EPS_);
        const float v0 = sc * slo, v1 = sc * shi;
        const int o = b * (C_ * E_) + tid * 2;
        if (mode == 2)      { out[o] = v0;    out[o + 1] = v1; }
        else if (mode == 0) { v_cum[o] = v0;  v_cum[o + 1] = v1; }
        else                { v_cum[o] += v0; v_cum[o + 1] += v1; }
    }
}

extern "C" void kernel_launch(void* const* d_in, const int* in_sizes, int n_in,
                              void* d_out, int out_size, void* d_ws, size_t ws_size,
                              hipStream_t stream) {
    const float* x = (const float*)d_in[0];
    const float* W = (const float*)d_in[1];
    float* out = (float*)d_out;

    unsigned* partial = (unsigned*)d_ws;   // 64*1024*80*4 = 21 MB
    float* v_cum = (float*)((char*)d_ws +
        (size_t)B_ * NSLOT_ * PROW_ * sizeof(unsigned));

    for (int t = 0; t < 3; ++t) {
        if (t == 0)
            caps_pass<true ><<<dim3(NBLK_), 256, 0, stream>>>(x, W, v_cum, partial);
        else
            caps_pass<false><<<dim3(NBLK_), 256, 0, stream>>>(x, W, v_cum, partial);
        caps_reduce<<<dim3(B_), 192, 0, stream>>>(partial, v_cum, out, t);
    }
}

// Round 9
// 184.940 us; speedup vs baseline: 1.9743x; 1.0616x over previous
//
#include <hip/hip_runtime.h>
#include <hip/hip_fp16.h>

#define B_ 64
#define N_ 4096
#define C_ 10
#define D_ 8
#define E_ 16
#define EPS_ 1e-7f
#define NT_ 4
#define NBLK_ (N_ / NT_)          // 1024 pass blocks
#define NSLOT_ NBLK_              // 1024 partial slots (one per block)
#define PROW_ 80                  // u32 per partial row (160 halfs)
#define WBROW_ 82                 // padded LDS writeback row stride (u32)

// bf16 truncation pack/unpack (register-resident uh, v_cum)
__device__ inline unsigned pk2(float a, float b) {
    return (__float_as_uint(a) >> 16) | (__float_as_uint(b) & 0xffff0000u);
}
__device__ inline float plo(unsigned u) { return __uint_as_float(u << 16); }
__device__ inline float phi(unsigned u) { return __uint_as_float(u & 0xffff0000u); }
__device__ inline unsigned hpack(float a, float b) {
    __half2 t = __floats2half2_rn(a, b);
    return *(unsigned*)&t;
}
__device__ inline float2 hunpack(unsigned u) {
    return __half22float2(*(const __half2*)&u);
}

// Block: 256 thr = 4 waves = (h: b-half) x (np: n-half). Thread owns TWO b
// (b0 = h*32 + bl, b1 = b0 + 16): each W ds_read_b128 broadcast feeds 8 FMAs.
// NT=4 -> 1024 blocks = 4 blocks/CU (16 waves/CU). np-halves combined via an
// LDS writeback buffer aliased over the dead W tile; one full-line coalesced
// partial write per block.
template <bool UNIFORM>
__global__ __launch_bounds__(256, 2) void caps_pass(
    const float* __restrict__ x, const float* __restrict__ W,
    const float* __restrict__ v_cum, unsigned* __restrict__ partial)
{
    __shared__ __align__(16) char smem[21504];
    float4*   wtile = (float4*)smem;        // NT_*320 = 1280 float4 = 20 KB
    unsigned* wb    = (unsigned*)smem;      // [64][WBROW_] u32 = 20992 B (alias)

    const int tid = (int)threadIdx.x;
    const int blk = (int)blockIdx.x;

    {   // stage W[blk*4 .. +4) -> LDS, coalesced float4 (5 per thread)
        const float4* g = (const float4*)(W + (size_t)blk * (NT_ * 1280));
#pragma unroll
        for (int i = 0; i < 5; ++i)
            wtile[i * 256 + tid] = g[i * 256 + tid];
    }

    const int wv   = tid >> 6;
    const int lane = tid & 63;
    const int eq   = lane & 3;
    const int bl   = lane >> 2;
    const int h    = wv & 1;
    const int np   = wv >> 1;
    const int b0   = h * 32 + bl;
    const int b1   = b0 + 16;

    unsigned vcp0[C_][2], vcp1[C_][2];
    if (!UNIFORM) {
#pragma unroll
        for (int c = 0; c < C_; ++c) {
            const float4 a = *(const float4*)(v_cum + (b0 * C_ + c) * E_ + eq * 4);
            vcp0[c][0] = pk2(a.x, a.y); vcp0[c][1] = pk2(a.z, a.w);
            const float4 d = *(const float4*)(v_cum + (b1 * C_ + c) * E_ + eq * 4);
            vcp1[c][0] = pk2(d.x, d.y); vcp1[c][1] = pk2(d.z, d.w);
        }
    }

    float4 acc0[C_], acc1[C_];
#pragma unroll
    for (int c = 0; c < C_; ++c) {
        acc0[c] = make_float4(0.f, 0.f, 0.f, 0.f);
        acc1[c] = make_float4(0.f, 0.f, 0.f, 0.f);
    }

    __syncthreads();

#pragma unroll 1
    for (int j = 0; j < 2; ++j) {
        const int nl = np * 2 + j;
        const int n  = blk * NT_ + nl;

        float xv0[D_], xv1[D_];
        {
            const float4* xp = (const float4*)(x + ((size_t)b0 * N_ + n) * D_);
            const float4 a = xp[0], d = xp[1];
            xv0[0]=a.x; xv0[1]=a.y; xv0[2]=a.z; xv0[3]=a.w;
            xv0[4]=d.x; xv0[5]=d.y; xv0[6]=d.z; xv0[7]=d.w;
        }
        {
            const float4* xp = (const float4*)(x + ((size_t)b1 * N_ + n) * D_);
            const float4 a = xp[0], d = xp[1];
            xv1[0]=a.x; xv1[1]=a.y; xv1[2]=a.z; xv1[3]=a.w;
            xv1[4]=d.x; xv1[5]=d.y; xv1[6]=d.z; xv1[7]=d.w;
        }

        const float4* wl = wtile + nl * 320 + eq;

        if (UNIFORM) {
#pragma unroll
            for (int c = 0; c < C_; ++c) {
#pragma unroll
                for (int d = 0; d < D_; ++d) {
                    const float4 wq = wl[c * 32 + d * 4];
                    acc0[c].x = fmaf(xv0[d], wq.x, acc0[c].x);
                    acc0[c].y = fmaf(xv0[d], wq.y, acc0[c].y);
                    acc0[c].z = fmaf(xv0[d], wq.z, acc0[c].z);
                    acc0[c].w = fmaf(xv0[d], wq.w, acc0[c].w);
                    acc1[c].x = fmaf(xv1[d], wq.x, acc1[c].x);
                    acc1[c].y = fmaf(xv1[d], wq.y, acc1[c].y);
                    acc1[c].z = fmaf(xv1[d], wq.z, acc1[c].z);
                    acc1[c].w = fmaf(xv1[d], wq.w, acc1[c].w);
                }
            }
        } else {
            unsigned uhp0[C_][2], uhp1[C_][2];
            float wgt0[C_], wgt1[C_];
#pragma unroll
            for (int c = 0; c < C_; ++c) {
                float4 u0 = make_float4(0.f, 0.f, 0.f, 0.f);
                float4 u1 = make_float4(0.f, 0.f, 0.f, 0.f);
#pragma unroll
                for (int d = 0; d < D_; ++d) {
                    const float4 wq = wl[c * 32 + d * 4];
                    u0.x = fmaf(xv0[d], wq.x, u0.x);
                    u0.y = fmaf(xv0[d], wq.y, u0.y);
                    u0.z = fmaf(xv0[d], wq.z, u0.z);
                    u0.w = fmaf(xv0[d], wq.w, u0.w);
                    u1.x = fmaf(xv1[d], wq.x, u1.x);
                    u1.y = fmaf(xv1[d], wq.y, u1.y);
                    u1.z = fmaf(xv1[d], wq.z, u1.z);
                    u1.w = fmaf(xv1[d], wq.w, u1.w);
                }
                float t0 = u0.x * plo(vcp0[c][0]);
                t0 = fmaf(u0.y, phi(vcp0[c][0]), t0);
                t0 = fmaf(u0.z, plo(vcp0[c][1]), t0);
                t0 = fmaf(u0.w, phi(vcp0[c][1]), t0);
                t0 += __shfl_xor(t0, 1); t0 += __shfl_xor(t0, 2);
                wgt0[c] = t0;
                float t1 = u1.x * plo(vcp1[c][0]);
                t1 = fmaf(u1.y, phi(vcp1[c][0]), t1);
                t1 = fmaf(u1.z, plo(vcp1[c][1]), t1);
                t1 = fmaf(u1.w, phi(vcp1[c][1]), t1);
                t1 += __shfl_xor(t1, 1); t1 += __shfl_xor(t1, 2);
                wgt1[c] = t1;
                uhp0[c][0] = pk2(u0.x, u0.y); uhp0[c][1] = pk2(u0.z, u0.w);
                uhp1[c][0] = pk2(u1.x, u1.y); uhp1[c][1] = pk2(u1.z, u1.w);
            }
            // softmax over C, no max-sub (|logit| <~ 15, exp safe in f32)
            float s0 = 0.f, s1 = 0.f;
#pragma unroll
            for (int c = 0; c < C_; ++c) {
                wgt0[c] = __expf(wgt0[c]); s0 += wgt0[c];
                wgt1[c] = __expf(wgt1[c]); s1 += wgt1[c];
            }
            const float i0 = 1.f / s0, i1 = 1.f / s1;
#pragma unroll
            for (int c = 0; c < C_; ++c) {
                const float g0 = wgt0[c] * i0, g1 = wgt1[c] * i1;
                acc0[c].x = fmaf(g0, plo(uhp0[c][0]), acc0[c].x);
                acc0[c].y = fmaf(g0, phi(uhp0[c][0]), acc0[c].y);
                acc0[c].z = fmaf(g0, plo(uhp0[c][1]), acc0[c].z);
                acc0[c].w = fmaf(g0, phi(uhp0[c][1]), acc0[c].w);
                acc1[c].x = fmaf(g1, plo(uhp1[c][0]), acc1[c].x);
                acc1[c].y = fmaf(g1, phi(uhp1[c][0]), acc1[c].y);
                acc1[c].z = fmaf(g1, plo(uhp1[c][1]), acc1[c].z);
                acc1[c].w = fmaf(g1, phi(uhp1[c][1]), acc1[c].w);
            }
        }
    }

    const float fold = UNIFORM ? 0.1f : 1.f;   // softmax(0) = 1/10 folded out

    __syncthreads();   // all W-tile reads done; smem is now the wb buffer

    if (np == 1) {     // np=1 waves deposit folded fp16 partials
#pragma unroll
        for (int c = 0; c < C_; ++c) {
            const uint2 p0 = make_uint2(hpack(acc0[c].x * fold, acc0[c].y * fold),
                                        hpack(acc0[c].z * fold, acc0[c].w * fold));
            *(uint2*)&wb[b0 * WBROW_ + c * 8 + eq * 2] = p0;
            const uint2 p1 = make_uint2(hpack(acc1[c].x * fold, acc1[c].y * fold),
                                        hpack(acc1[c].z * fold, acc1[c].w * fold));
            *(uint2*)&wb[b1 * WBROW_ + c * 8 + eq * 2] = p1;
        }
    }
    __syncthreads();
    if (np == 0) {     // np=0 waves add their half and repack
#pragma unroll
        for (int c = 0; c < C_; ++c) {
            uint2 p0 = *(uint2*)&wb[b0 * WBROW_ + c * 8 + eq * 2];
            const float2 a0 = hunpack(p0.x), a1 = hunpack(p0.y);
            p0.x = hpack(a0.x + acc0[c].x * fold, a0.y + acc0[c].y * fold);
            p0.y = hpack(a1.x + acc0[c].z * fold, a1.y + acc0[c].w * fold);
            *(uint2*)&wb[b0 * WBROW_ + c * 8 + eq * 2] = p0;
            uint2 p1 = *(uint2*)&wb[b1 * WBROW_ + c * 8 + eq * 2];
            const float2 d0 = hunpack(p1.x), d1 = hunpack(p1.y);
            p1.x = hpack(d0.x + acc1[c].x * fold, d0.y + acc1[c].y * fold);
            p1.y = hpack(d1.x + acc1[c].z * fold, d1.y + acc1[c].w * fold);
            *(uint2*)&wb[b1 * WBROW_ + c * 8 + eq * 2] = p1;
        }
    }
    __syncthreads();

    // full-line coalesced write-out: 2560 uint2 by 256 threads
#pragma unroll
    for (int it = 0; it < 10; ++it) {
        const int i2   = it * 256 + tid;     // [0, 2560)
        const int bb   = i2 / 40;
        const int col2 = i2 - bb * 40;
        const uint2 val = *(const uint2*)&wb[bb * WBROW_ + col2 * 2];
        *(uint2*)(partial + ((size_t)bb * NSLOT_ + blk) * PROW_ + col2 * 2) = val;
    }
}

// Block per b: sum partial[b][*][col] (fp16x2 rows, coalesced), squash, update.
// mode: 0 = v_cum = v, 1 = v_cum += v, 2 = out = v
__global__ __launch_bounds__(192) void caps_reduce(
    const unsigned* __restrict__ partial, float* __restrict__ v_cum,
    float* __restrict__ out, int mode)
{
    const int b = (int)blockIdx.x;
    const int tid = (int)threadIdx.x;
    __shared__ float redlo[2][PROW_], redhi[2][PROW_];
    if (tid < 2 * PROW_) {
        const int col = tid % PROW_;
        const int gh  = tid / PROW_;
        const unsigned* base =
            partial + ((size_t)b * NSLOT_ + (size_t)gh * (NSLOT_ / 2)) * PROW_ + col;
        float a0 = 0.f, a1 = 0.f, c0 = 0.f, c1 = 0.f;
        for (int k = 0; k < NSLOT_ / 2; k += 2) {
            const unsigned u0 = base[(size_t)k * PROW_];
            const unsigned u1 = base[(size_t)(k + 1) * PROW_];
            const float2 f0 = __half22float2(*(const __half2*)&u0);
            const float2 f1 = __half22float2(*(const __half2*)&u1);
            a0 += f0.x; c0 += f0.y;
            a1 += f1.x; c1 += f1.y;
        }
        redlo[gh][col] = a0 + a1;
        redhi[gh][col] = c0 + c1;
    }
    __syncthreads();
    if (tid < PROW_) {
        const float slo = redlo[0][tid] + redlo[1][tid];
        const float shi = redhi[0][tid] + redhi[1][tid];
        float p = slo * slo + shi * shi;
        p += __shfl_xor(p, 1); p += __shfl_xor(p, 2); p += __shfl_xor(p, 4);
        const float sc = (p / (1.f + p)) * rsqrtf(p + EPS_);
        const float v0 = sc * slo, v1 = sc * shi;
        const int o = b * (C_ * E_) + tid * 2;
        if (mode == 2)      { out[o] = v0;    out[o + 1] = v1; }
        else if (mode == 0) { v_cum[o] = v0;  v_cum[o + 1] = v1; }
        else                { v_cum[o] += v0; v_cum[o + 1] += v1; }
    }
}

extern "C" void kernel_launch(void* const* d_in, const int* in_sizes, int n_in,
                              void* d_out, int out_size, void* d_ws, size_t ws_size,
                              hipStream_t stream) {
    const float* x = (const float*)d_in[0];
    const float* W = (const float*)d_in[1];
    float* out = (float*)d_out;

    unsigned* partial = (unsigned*)d_ws;   // 64*1024*80*4 = 21 MB
    float* v_cum = (float*)((char*)d_ws +
        (size_t)B_ * NSLOT_ * PROW_ * sizeof(unsigned));

    for (int t = 0; t < 3; ++t) {
        if (t == 0)
            caps_pass<true ><<<dim3(NBLK_), 256, 0, stream>>>(x, W, v_cum, partial);
        else
            caps_pass<false><<<dim3(NBLK_), 256, 0, stream>>>(x, W, v_cum, partial);
        caps_reduce<<<dim3(B_), 192, 0, stream>>>(partial, v_cum, out, t);
    }
}